// Round 12
// baseline (135.877 us; speedup 1.0000x reference)
//
#include <hip/hip_runtime.h>
#include <hip/hip_bf16.h>

typedef __attribute__((ext_vector_type(8))) short short8;
typedef __attribute__((ext_vector_type(4))) short short4v;
typedef __attribute__((ext_vector_type(4))) float f32x4;

#define TT 4096
#define DM 1024
#define NH 16
#define NPROJ 1280   // 128 qs + 128 ks + 256 qg + 256 kg + 512 v
#define DATTN 512

static __device__ __forceinline__ short f2bf(float f) {
  __hip_bfloat16 h = __float2bfloat16(f);
  return *reinterpret_cast<short*>(&h);
}
static __device__ __forceinline__ float bf2f(__hip_bfloat16 h) { return __bfloat162float(h); }
static __device__ __forceinline__ unsigned pk2(float a, float b) {
  float2 t; t.x = a; t.y = b;
  __hip_bfloat162 r = __float22bfloat162_rn(t);
  return *reinterpret_cast<unsigned*>(&r);
}

// ---------------- fp32 -> bf16 convert (x, out_w) ----------------
__global__ __launch_bounds__(256) void k_f32_to_bf16(const float* __restrict__ in,
                                                     __hip_bfloat16* __restrict__ out, int n4) {
  int i = blockIdx.x * blockDim.x + threadIdx.x;
  if (i >= n4) return;
  float4 v = reinterpret_cast<const float4*>(in)[i];
  short4v o;
  o[0] = f2bf(v.x); o[1] = f2bf(v.y); o[2] = f2bf(v.z); o[3] = f2bf(v.w);
  reinterpret_cast<short4v*>(out)[i] = o;
}

// ---------------- concat 5 weight matrices into (1280,1024) bf16 ----------------
__global__ __launch_bounds__(256) void k_pack_wcat(const float* __restrict__ qs,
    const float* __restrict__ ks, const float* __restrict__ qg, const float* __restrict__ kg,
    const float* __restrict__ vw, __hip_bfloat16* __restrict__ w, int n4) {
  int i = blockIdx.x * blockDim.x + threadIdx.x;
  if (i >= n4) return;
  int idx = i * 4;
  int row = idx >> 10;
  int col = idx & 1023;
  const float* src;
  if (row < 128)      src = qs + (size_t)row * DM;
  else if (row < 256) src = ks + (size_t)(row - 128) * DM;
  else if (row < 512) src = qg + (size_t)(row - 256) * DM;
  else if (row < 768) src = kg + (size_t)(row - 512) * DM;
  else                src = vw + (size_t)(row - 768) * DM;
  float4 v = *reinterpret_cast<const float4*>(src + col);
  short4v o;
  o[0] = f2bf(v.x); o[1] = f2bf(v.y); o[2] = f2bf(v.z); o[3] = f2bf(v.w);
  *reinterpret_cast<short4v*>(w + idx) = o;
}

// ---------------- bf16 GEMM, B^T layout: C[m][n] = sum_k A[m][k]*B[n][k] ----------------
template<int OUT_BF16>
__global__ __launch_bounds__(256) void k_gemm_bt(const __hip_bfloat16* __restrict__ A,
    const __hip_bfloat16* __restrict__ B, void* __restrict__ Cv, int M, int N, int K) {
  __shared__ alignas(16) __hip_bfloat16 lA[128 * 32];
  __shared__ alignas(16) __hip_bfloat16 lB[128 * 32];
  const int tid = threadIdx.x;
  const int lane = tid & 63;
  const int wid = tid >> 6;
  const int m0 = blockIdx.x * 128, n0 = blockIdx.y * 128;
  const int wm = (wid >> 1) * 64, wn = (wid & 1) * 64;
  const int srow = tid >> 2;          // 0..63
  const int scol = (tid & 3) * 8;     // bf16 elements
  const int fr = lane & 15, fk = (lane >> 4) * 8;
  f32x4 acc[4][4];
  const f32x4 zz = {0.f, 0.f, 0.f, 0.f};
#pragma unroll
  for (int m = 0; m < 4; ++m)
#pragma unroll
    for (int n = 0; n < 4; ++n) acc[m][n] = zz;

  for (int kt = 0; kt < K; kt += 32) {
    __syncthreads();
    {
      const __hip_bfloat16* ga0 = A + (size_t)(m0 + srow) * K + kt + scol;
      const __hip_bfloat16* ga1 = A + (size_t)(m0 + 64 + srow) * K + kt + scol;
      const __hip_bfloat16* gb0 = B + (size_t)(n0 + srow) * K + kt + scol;
      const __hip_bfloat16* gb1 = B + (size_t)(n0 + 64 + srow) * K + kt + scol;
      __builtin_amdgcn_global_load_lds((const __attribute__((address_space(1))) void*)ga0,
          (__attribute__((address_space(3))) void*)(lA + srow * 32 + scol), 16, 0, 0);
      __builtin_amdgcn_global_load_lds((const __attribute__((address_space(1))) void*)ga1,
          (__attribute__((address_space(3))) void*)(lA + (64 + srow) * 32 + scol), 16, 0, 0);
      __builtin_amdgcn_global_load_lds((const __attribute__((address_space(1))) void*)gb0,
          (__attribute__((address_space(3))) void*)(lB + srow * 32 + scol), 16, 0, 0);
      __builtin_amdgcn_global_load_lds((const __attribute__((address_space(1))) void*)gb1,
          (__attribute__((address_space(3))) void*)(lB + (64 + srow) * 32 + scol), 16, 0, 0);
    }
    __syncthreads();
    short8 af[4], bfr[4];
#pragma unroll
    for (int m = 0; m < 4; ++m)
      af[m] = *reinterpret_cast<const short8*>(lA + (wm + m * 16 + fr) * 32 + fk);
#pragma unroll
    for (int n = 0; n < 4; ++n)
      bfr[n] = *reinterpret_cast<const short8*>(lB + (wn + n * 16 + fr) * 32 + fk);
#pragma unroll
    for (int m = 0; m < 4; ++m)
#pragma unroll
      for (int n = 0; n < 4; ++n)
        acc[m][n] = __builtin_amdgcn_mfma_f32_16x16x32_bf16(af[m], bfr[n], acc[m][n], 0, 0, 0);
  }
  const int cr = (lane >> 4) * 4, cc = lane & 15;
#pragma unroll
  for (int m = 0; m < 4; ++m)
#pragma unroll
    for (int n = 0; n < 4; ++n)
#pragma unroll
      for (int j = 0; j < 4; ++j) {
        const int row = m0 + wm + m * 16 + cr + j;
        const int col = n0 + wn + n * 16 + cc;
        if (OUT_BF16)
          ((__hip_bfloat16*)Cv)[(size_t)row * N + col] = __float2bfloat16(acc[m][n][j]);
        else
          ((float*)Cv)[(size_t)row * N + col] = acc[m][n][j];
      }
}

// ---------------- RoPE + pack Q/K (H,T,32) and V^T (H,32,T) ----------------
// qscale folds 1/sqrt(24) * exp(logit_scale) * log2(e)  (softmax uses exp2)
__global__ __launch_bounds__(256) void k_rope_pack(const __hip_bfloat16* __restrict__ proj,
    const float* __restrict__ ls, const int* __restrict__ posp,
    __hip_bfloat16* __restrict__ Qp, __hip_bfloat16* __restrict__ Kp,
    __hip_bfloat16* __restrict__ Vt) {
  const int gid = blockIdx.x * blockDim.x + threadIdx.x;  // T*NH, t fastest
  const int t = gid & (TT - 1);
  const int h = gid >> 12;
  const __hip_bfloat16* pr = proj + (size_t)t * NPROJ;
  const float qscale = 0.20412414523193154f * 1.4426950408889634f * __expf(ls[h]);
  const float pos = (float)(t + posp[0]);
  const float invf[8] = {1.0f, 0.31622776601683794f, 0.1f, 0.031622776601683794f,
                         0.01f, 0.0031622776601683794f, 0.001f, 0.00031622776601683794f};
  short8 qv[4], kv[4];
  const short8 z8 = {0, 0, 0, 0, 0, 0, 0, 0};
  qv[3] = z8; kv[3] = z8;
#pragma unroll
  for (int i = 0; i < 8; ++i) {
    qv[0][i] = f2bf(bf2f(pr[h * 8 + i]) * qscale);
    kv[0][i] = f2bf(bf2f(pr[128 + h * 8 + i]));
  }
#pragma unroll
  for (int i = 0; i < 8; ++i) {
    const float ang = pos * invf[i];
    float ss, cc;
    __sincosf(ang, &ss, &cc);
    const float x1q = bf2f(pr[256 + h * 16 + i]), x2q = bf2f(pr[256 + h * 16 + 8 + i]);
    const float x1k = bf2f(pr[512 + h * 16 + i]), x2k = bf2f(pr[512 + h * 16 + 8 + i]);
    qv[1][i] = f2bf((x1q * cc - x2q * ss) * qscale);
    qv[2][i] = f2bf((x1q * ss + x2q * cc) * qscale);
    kv[1][i] = f2bf(x1k * cc - x2k * ss);
    kv[2][i] = f2bf(x1k * ss + x2k * cc);
  }
  short8* qdst = reinterpret_cast<short8*>(Qp + ((size_t)h * TT + t) * 32);
  short8* kdst = reinterpret_cast<short8*>(Kp + ((size_t)h * TT + t) * 32);
#pragma unroll
  for (int p = 0; p < 4; ++p) { qdst[p] = qv[p]; kdst[p] = kv[p]; }
#pragma unroll
  for (int i = 0; i < 32; ++i)
    Vt[((size_t)h * 32 + i) * TT + t] = pr[768 + h * 32 + i];
}

// ---------------- causal flash attention, 3-deep pipeline + counted vmcnt ----------------
// 1024 blocks x 4 waves; block = (head, 64-row q-block), LPT dispatch (qb descending).
// 3 LDS K/V buffers; per tile: s_waitcnt vmcnt(2) (current tile's pair only; next
// stays in flight) + raw s_barrier + sched_barrier; prefetch issued after barrier
// (target buffer last read 2 barriers ago -> WAR-safe). No compiler vmcnt(0) drain.
// QK accumulator initialized to -mshift (running max folded into MFMA, no subs).
// LDS layouts = exact read order (every ds_read = base + lane*16, conflict-free).
__global__ __launch_bounds__(256) void k_attn(const __hip_bfloat16* __restrict__ Qp,
    const __hip_bfloat16* __restrict__ Kp, const __hip_bfloat16* __restrict__ Vt,
    __hip_bfloat16* __restrict__ Ob) {
  __shared__ alignas(16) __hip_bfloat16 lK[3][64 * 32];   // 4KB each
  __shared__ alignas(16) __hip_bfloat16 lV[3][32 * 64];   // 4KB each
  __shared__ alignas(16) __hip_bfloat16 Plds[4][16][72];
  const int lin = blockIdx.x;           // 0..1023
  const int xcd = lin & 7;
  const int idx = lin >> 3;             // 0..127
  const int h = xcd * 2 + (idx & 1);    // 2 heads per XCD
  const int qb = 63 - (idx >> 1);       // DESCENDING: big blocks first (LPT)
  const int nt = qb + 1;
  const int tid = threadIdx.x;
  const int lane = tid & 63, w = tid >> 6;
  const int g = lane >> 4, c = lane & 15;
  // staging source mapping (inverse of the LDS read permutation)
  const int krow = (tid >> 6) * 16 + (tid & 15);           // kv row within tile
  const int kcol = ((tid >> 4) & 3) * 8;                   // dim slot
  const int vrow = ((tid >> 6) & 1) * 16 + (tid & 15);     // d row
  const int vcol = ((tid >> 7) & 1) * 32 + ((tid >> 4) & 3) * 8;  // kv slot within tile
  const __hip_bfloat16* Kh = Kp + (size_t)h * TT * 32 + (size_t)krow * 32 + kcol;
  const __hip_bfloat16* Vh = Vt + (size_t)h * 32 * TT + (size_t)vrow * TT + vcol;
  const f32x4 zz = {0.f, 0.f, 0.f, 0.f};

  const int qrow = qb * 64 + w * 16 + c;
  const short8 qf =
      *reinterpret_cast<const short8*>(Qp + ((size_t)h * TT + qrow) * 32 + 8 * g);
  f32x4 o0 = zz, o1 = zz;
  float mshift = 0.f;    // running max in logit units (folded into MFMA C-init)
  float lsum = 0.f;

  auto stage = [&](int tile, int buf) {
    const int kv = tile * 64;
    __builtin_amdgcn_global_load_lds(
        (const __attribute__((address_space(1))) void*)(Kh + (size_t)kv * 32),
        (__attribute__((address_space(3))) void*)(lK[buf] + tid * 8), 16, 0, 0);
    __builtin_amdgcn_global_load_lds(
        (const __attribute__((address_space(1))) void*)(Vh + kv),
        (__attribute__((address_space(3))) void*)(lV[buf] + tid * 8), 16, 0, 0);
  };

  stage(0, 0);
  if (nt > 1) stage(1, 1);
  int cur = 0;
  for (int it = 0; it < nt; ++it) {
    if (it + 1 < nt) {
      asm volatile("s_waitcnt vmcnt(2)" ::: "memory");   // current tile's pair landed
    } else {
      asm volatile("s_waitcnt vmcnt(0)" ::: "memory");   // last tile: full drain
    }
    __builtin_amdgcn_s_barrier();
    __builtin_amdgcn_sched_barrier(0);
    if (it + 2 < nt) stage(it + 2, cur == 0 ? 2 : cur - 1);  // (it+2)%3 == (cur+2)%3
    // K fragments: addr = base + lane*16 (conflict-free)
    const char* kb = (const char*)lK[cur];
    short8 kf[4];
#pragma unroll
    for (int ct = 0; ct < 4; ++ct)
      kf[ct] = *reinterpret_cast<const short8*>(kb + ct * 1024 + lane * 16);
    // V fragments: addr = base + lane*16 (conflict-free)
    const char* vb = (const char*)lV[cur];
    const short8 v00 = *reinterpret_cast<const short8*>(vb + lane * 16);
    const short8 v10 = *reinterpret_cast<const short8*>(vb + 1024 + lane * 16);
    const short8 v01 = *reinterpret_cast<const short8*>(vb + 2048 + lane * 16);
    const short8 v11 = *reinterpret_cast<const short8*>(vb + 3072 + lane * 16);
    // QK^T with -mshift pre-folded into the accumulator (no per-element subs)
    const f32x4 cin = {-mshift, -mshift, -mshift, -mshift};
    f32x4 s[4];
    __builtin_amdgcn_s_setprio(1);
#pragma unroll
    for (int ct = 0; ct < 4; ++ct)
      s[ct] = __builtin_amdgcn_mfma_f32_16x16x32_bf16(kf[ct], qf, cin, 0, 0, 0);  // swapped
    __builtin_amdgcn_s_setprio(0);
    if (it == nt - 1) {  // diagonal tile: mask k > q
#pragma unroll
      for (int ct = 0; ct < 4; ++ct)
#pragma unroll
        for (int j = 0; j < 4; ++j)
          if (ct * 16 + g * 4 + j > w * 16 + c) s[ct][j] = -1e30f;
    }
    // in-lane max over 16 shifted scores
    float m01 = fmaxf(fmaxf(s[0][0], s[0][1]), fmaxf(s[0][2], s[0][3]));
    float m23 = fmaxf(fmaxf(s[1][0], s[1][1]), fmaxf(s[1][2], s[1][3]));
    float m45 = fmaxf(fmaxf(s[2][0], s[2][1]), fmaxf(s[2][2], s[2][3]));
    float m67 = fmaxf(fmaxf(s[3][0], s[3][1]), fmaxf(s[3][2], s[3][3]));
    float pm_ = fmaxf(fmaxf(m01, m23), fmaxf(m45, m67));
    if (__any(pm_ > 8.0f)) {  // defer-max trigger (shift-invariant)
      float pm2 = fmaxf(pm_, __shfl_xor(pm_, 16, 64));
      pm2 = fmaxf(pm2, __shfl_xor(pm2, 32, 64));
      const float delta = fmaxf(pm2, 0.f);
      const float alpha = exp2f(-delta);
      mshift += delta;
      lsum *= alpha;
#pragma unroll
      for (int j = 0; j < 4; ++j) { o0[j] *= alpha; o1[j] *= alpha; }
#pragma unroll
      for (int ct = 0; ct < 4; ++ct)
#pragma unroll
        for (int j = 0; j < 4; ++j) s[ct][j] -= delta;
    }
    float ts = 0.f;
#pragma unroll
    for (int ct = 0; ct < 4; ++ct) {
#pragma unroll
      for (int j = 0; j < 4; ++j) s[ct][j] = exp2f(s[ct][j]);
      ts += (s[ct][0] + s[ct][1]) + (s[ct][2] + s[ct][3]);
    }
    lsum += ts;
    // P -> LDS: 4x ds_write_b64, per-wave private slice (2-way max: free)
#pragma unroll
    for (int ct = 0; ct < 4; ++ct) {
      uint2 u;
      u.x = pk2(s[ct][0], s[ct][1]);
      u.y = pk2(s[ct][2], s[ct][3]);
      *reinterpret_cast<uint2*>(&Plds[w][c][ct * 16 + g * 4]) = u;
    }
    const short8 pf0 = *reinterpret_cast<const short8*>(&Plds[w][c][8 * g]);
    const short8 pf1 = *reinterpret_cast<const short8*>(&Plds[w][c][32 + 8 * g]);
    // O^T: C col = q-row = lane c
    __builtin_amdgcn_s_setprio(1);
    o0 = __builtin_amdgcn_mfma_f32_16x16x32_bf16(v00, pf0, o0, 0, 0, 0);
    o0 = __builtin_amdgcn_mfma_f32_16x16x32_bf16(v01, pf1, o0, 0, 0, 0);
    o1 = __builtin_amdgcn_mfma_f32_16x16x32_bf16(v10, pf0, o1, 0, 0, 0);
    o1 = __builtin_amdgcn_mfma_f32_16x16x32_bf16(v11, pf1, o1, 0, 0, 0);
    __builtin_amdgcn_s_setprio(0);
    cur = (cur == 2) ? 0 : cur + 1;
  }
  // final lsum reduce across g-lanes of row c; write Ob
  lsum += __shfl_xor(lsum, 16, 64);
  lsum += __shfl_xor(lsum, 32, 64);
  const float inv = 1.0f / lsum;
  __hip_bfloat16* dst = Ob + (size_t)qrow * DATTN + h * 32;
  short4v w0, w1;
#pragma unroll
  for (int j = 0; j < 4; ++j) { w0[j] = f2bf(o0[j] * inv); w1[j] = f2bf(o1[j] * inv); }
  *reinterpret_cast<short4v*>(dst + g * 4) = w0;
  *reinterpret_cast<short4v*>(dst + 16 + g * 4) = w1;
}

extern "C" void kernel_launch(void* const* d_in, const int* in_sizes, int n_in,
                              void* d_out, int out_size, void* d_ws, size_t ws_size,
                              hipStream_t stream) {
  const float* x   = (const float*)d_in[0];
  const float* qsw = (const float*)d_in[1];
  const float* ksw = (const float*)d_in[2];
  const float* qgw = (const float*)d_in[3];
  const float* kgw = (const float*)d_in[4];
  const float* vw  = (const float*)d_in[5];
  const float* ow  = (const float*)d_in[6];
  const float* ls  = (const float*)d_in[7];
  const int* posp  = (const int*)d_in[9];

  size_t off = 0;
  auto alloc = [&](size_t bytes) {
    char* p = (char*)d_ws + off;
    off += (bytes + 255) & ~(size_t)255;
    return (void*)p;
  };
  __hip_bfloat16* Xbf  = (__hip_bfloat16*)alloc((size_t)TT * DM * 2);
  __hip_bfloat16* Wcat = (__hip_bfloat16*)alloc((size_t)NPROJ * DM * 2);
  __hip_bfloat16* OW   = (__hip_bfloat16*)alloc((size_t)DM * DATTN * 2);
  __hip_bfloat16* proj = (__hip_bfloat16*)alloc((size_t)TT * NPROJ * 2);
  __hip_bfloat16* Qp   = (__hip_bfloat16*)alloc((size_t)NH * TT * 32 * 2);
  __hip_bfloat16* Kpk  = (__hip_bfloat16*)alloc((size_t)NH * TT * 32 * 2);
  __hip_bfloat16* Vt   = (__hip_bfloat16*)alloc((size_t)NH * 32 * TT * 2);
  __hip_bfloat16* Ob   = (__hip_bfloat16*)alloc((size_t)TT * DATTN * 2);

  k_f32_to_bf16<<<dim3((TT * DM / 4) / 256), 256, 0, stream>>>(x, Xbf, TT * DM / 4);
  k_f32_to_bf16<<<dim3((DM * DATTN / 4) / 256), 256, 0, stream>>>(ow, OW, DM * DATTN / 4);
  k_pack_wcat<<<dim3((NPROJ * DM / 4) / 256), 256, 0, stream>>>(qsw, ksw, qgw, kgw, vw, Wcat,
                                                                NPROJ * DM / 4);
  k_gemm_bt<1><<<dim3(TT / 128, NPROJ / 128), 256, 0, stream>>>(Xbf, Wcat, (void*)proj,
                                                                TT, NPROJ, DM);
  k_rope_pack<<<dim3(TT * NH / 256), 256, 0, stream>>>(proj, ls, posp, Qp, Kpk, Vt);
  k_attn<<<dim3(1024), 256, 0, stream>>>(Qp, Kpk, Vt, Ob);
  k_gemm_bt<0><<<dim3(TT / 128, DM / 128), 256, 0, stream>>>(Ob, OW, (void*)d_out,
                                                             TT, DM, DATTN);
}

// Round 13
// 133.599 us; speedup vs baseline: 1.0171x; 1.0171x over previous
//
#include <hip/hip_runtime.h>
#include <hip/hip_bf16.h>

typedef __attribute__((ext_vector_type(8))) short short8;
typedef __attribute__((ext_vector_type(4))) short short4v;
typedef __attribute__((ext_vector_type(4))) float f32x4;

#define TT 4096
#define DM 1024
#define NH 16
#define NPROJ 1280   // 128 qs + 128 ks + 256 qg + 256 kg + 512 v
#define DATTN 512

static __device__ __forceinline__ short f2bf(float f) {
  __hip_bfloat16 h = __float2bfloat16(f);
  return *reinterpret_cast<short*>(&h);
}
static __device__ __forceinline__ float bf2f(__hip_bfloat16 h) { return __bfloat162float(h); }
static __device__ __forceinline__ unsigned pk2(float a, float b) {
  float2 t; t.x = a; t.y = b;
  __hip_bfloat162 r = __float22bfloat162_rn(t);
  return *reinterpret_cast<unsigned*>(&r);
}

// ---------------- fp32 -> bf16 convert (x, out_w) ----------------
__global__ __launch_bounds__(256) void k_f32_to_bf16(const float* __restrict__ in,
                                                     __hip_bfloat16* __restrict__ out, int n4) {
  int i = blockIdx.x * blockDim.x + threadIdx.x;
  if (i >= n4) return;
  float4 v = reinterpret_cast<const float4*>(in)[i];
  short4v o;
  o[0] = f2bf(v.x); o[1] = f2bf(v.y); o[2] = f2bf(v.z); o[3] = f2bf(v.w);
  reinterpret_cast<short4v*>(out)[i] = o;
}

// ---------------- concat 5 weight matrices into (1280,1024) bf16 ----------------
__global__ __launch_bounds__(256) void k_pack_wcat(const float* __restrict__ qs,
    const float* __restrict__ ks, const float* __restrict__ qg, const float* __restrict__ kg,
    const float* __restrict__ vw, __hip_bfloat16* __restrict__ w, int n4) {
  int i = blockIdx.x * blockDim.x + threadIdx.x;
  if (i >= n4) return;
  int idx = i * 4;
  int row = idx >> 10;
  int col = idx & 1023;
  const float* src;
  if (row < 128)      src = qs + (size_t)row * DM;
  else if (row < 256) src = ks + (size_t)(row - 128) * DM;
  else if (row < 512) src = qg + (size_t)(row - 256) * DM;
  else if (row < 768) src = kg + (size_t)(row - 512) * DM;
  else                src = vw + (size_t)(row - 768) * DM;
  float4 v = *reinterpret_cast<const float4*>(src + col);
  short4v o;
  o[0] = f2bf(v.x); o[1] = f2bf(v.y); o[2] = f2bf(v.z); o[3] = f2bf(v.w);
  *reinterpret_cast<short4v*>(w + idx) = o;
}

// ---------------- bf16 GEMM, B^T layout: C[m][n] = sum_k A[m][k]*B[n][k] ----------------
template<int OUT_BF16>
__global__ __launch_bounds__(256) void k_gemm_bt(const __hip_bfloat16* __restrict__ A,
    const __hip_bfloat16* __restrict__ B, void* __restrict__ Cv, int M, int N, int K) {
  __shared__ alignas(16) __hip_bfloat16 lA[128 * 32];
  __shared__ alignas(16) __hip_bfloat16 lB[128 * 32];
  const int tid = threadIdx.x;
  const int lane = tid & 63;
  const int wid = tid >> 6;
  const int m0 = blockIdx.x * 128, n0 = blockIdx.y * 128;
  const int wm = (wid >> 1) * 64, wn = (wid & 1) * 64;
  const int srow = tid >> 2;          // 0..63
  const int scol = (tid & 3) * 8;     // bf16 elements
  const int fr = lane & 15, fk = (lane >> 4) * 8;
  f32x4 acc[4][4];
  const f32x4 zz = {0.f, 0.f, 0.f, 0.f};
#pragma unroll
  for (int m = 0; m < 4; ++m)
#pragma unroll
    for (int n = 0; n < 4; ++n) acc[m][n] = zz;

  for (int kt = 0; kt < K; kt += 32) {
    __syncthreads();
    {
      const __hip_bfloat16* ga0 = A + (size_t)(m0 + srow) * K + kt + scol;
      const __hip_bfloat16* ga1 = A + (size_t)(m0 + 64 + srow) * K + kt + scol;
      const __hip_bfloat16* gb0 = B + (size_t)(n0 + srow) * K + kt + scol;
      const __hip_bfloat16* gb1 = B + (size_t)(n0 + 64 + srow) * K + kt + scol;
      __builtin_amdgcn_global_load_lds((const __attribute__((address_space(1))) void*)ga0,
          (__attribute__((address_space(3))) void*)(lA + srow * 32 + scol), 16, 0, 0);
      __builtin_amdgcn_global_load_lds((const __attribute__((address_space(1))) void*)ga1,
          (__attribute__((address_space(3))) void*)(lA + (64 + srow) * 32 + scol), 16, 0, 0);
      __builtin_amdgcn_global_load_lds((const __attribute__((address_space(1))) void*)gb0,
          (__attribute__((address_space(3))) void*)(lB + srow * 32 + scol), 16, 0, 0);
      __builtin_amdgcn_global_load_lds((const __attribute__((address_space(1))) void*)gb1,
          (__attribute__((address_space(3))) void*)(lB + (64 + srow) * 32 + scol), 16, 0, 0);
    }
    __syncthreads();
    short8 af[4], bfr[4];
#pragma unroll
    for (int m = 0; m < 4; ++m)
      af[m] = *reinterpret_cast<const short8*>(lA + (wm + m * 16 + fr) * 32 + fk);
#pragma unroll
    for (int n = 0; n < 4; ++n)
      bfr[n] = *reinterpret_cast<const short8*>(lB + (wn + n * 16 + fr) * 32 + fk);
#pragma unroll
    for (int m = 0; m < 4; ++m)
#pragma unroll
      for (int n = 0; n < 4; ++n)
        acc[m][n] = __builtin_amdgcn_mfma_f32_16x16x32_bf16(af[m], bfr[n], acc[m][n], 0, 0, 0);
  }
  const int cr = (lane >> 4) * 4, cc = lane & 15;
#pragma unroll
  for (int m = 0; m < 4; ++m)
#pragma unroll
    for (int n = 0; n < 4; ++n)
#pragma unroll
      for (int j = 0; j < 4; ++j) {
        const int row = m0 + wm + m * 16 + cr + j;
        const int col = n0 + wn + n * 16 + cc;
        if (OUT_BF16)
          ((__hip_bfloat16*)Cv)[(size_t)row * N + col] = __float2bfloat16(acc[m][n][j]);
        else
          ((float*)Cv)[(size_t)row * N + col] = acc[m][n][j];
      }
}

// ---------------- RoPE + pack Q/K (H,T,32) and V^T (H,32,T) ----------------
// qscale folds 1/sqrt(24) * exp(logit_scale) * log2(e)  (softmax uses exp2)
__global__ __launch_bounds__(256) void k_rope_pack(const __hip_bfloat16* __restrict__ proj,
    const float* __restrict__ ls, const int* __restrict__ posp,
    __hip_bfloat16* __restrict__ Qp, __hip_bfloat16* __restrict__ Kp,
    __hip_bfloat16* __restrict__ Vt) {
  const int gid = blockIdx.x * blockDim.x + threadIdx.x;  // T*NH, t fastest
  const int t = gid & (TT - 1);
  const int h = gid >> 12;
  const __hip_bfloat16* pr = proj + (size_t)t * NPROJ;
  const float qscale = 0.20412414523193154f * 1.4426950408889634f * __expf(ls[h]);
  const float pos = (float)(t + posp[0]);
  const float invf[8] = {1.0f, 0.31622776601683794f, 0.1f, 0.031622776601683794f,
                         0.01f, 0.0031622776601683794f, 0.001f, 0.00031622776601683794f};
  short8 qv[4], kv[4];
  const short8 z8 = {0, 0, 0, 0, 0, 0, 0, 0};
  qv[3] = z8; kv[3] = z8;
#pragma unroll
  for (int i = 0; i < 8; ++i) {
    qv[0][i] = f2bf(bf2f(pr[h * 8 + i]) * qscale);
    kv[0][i] = f2bf(bf2f(pr[128 + h * 8 + i]));
  }
#pragma unroll
  for (int i = 0; i < 8; ++i) {
    const float ang = pos * invf[i];
    float ss, cc;
    __sincosf(ang, &ss, &cc);
    const float x1q = bf2f(pr[256 + h * 16 + i]), x2q = bf2f(pr[256 + h * 16 + 8 + i]);
    const float x1k = bf2f(pr[512 + h * 16 + i]), x2k = bf2f(pr[512 + h * 16 + 8 + i]);
    qv[1][i] = f2bf((x1q * cc - x2q * ss) * qscale);
    qv[2][i] = f2bf((x1q * ss + x2q * cc) * qscale);
    kv[1][i] = f2bf(x1k * cc - x2k * ss);
    kv[2][i] = f2bf(x1k * ss + x2k * cc);
  }
  short8* qdst = reinterpret_cast<short8*>(Qp + ((size_t)h * TT + t) * 32);
  short8* kdst = reinterpret_cast<short8*>(Kp + ((size_t)h * TT + t) * 32);
#pragma unroll
  for (int p = 0; p < 4; ++p) { qdst[p] = qv[p]; kdst[p] = kv[p]; }
#pragma unroll
  for (int i = 0; i < 32; ++i)
    Vt[((size_t)h * 32 + i) * TT + t] = pr[768 + h * 32 + i];
}

// ---------------- causal flash attention, LDS K/V + in-register pi-permuted PV ----------
// 1024 blocks x 4 waves; block = (head, 64-row q-block), LPT dispatch (qb descending).
// LDS layouts = exact read order (K/V staged via global_load_lds, rule #21).
// PV uses K-position permutation pi(8g+m) = (m<4 ? 4g+m : 16+4g+m-4) on BOTH operands:
//   B-frag = lane's OWN packed s values (P never touches LDS — kills the round trip);
//   A-frag = V^T read from LDS as 2x ds_read_b64 per MFMA (4-way conflict, off-chain).
__global__ __launch_bounds__(256) void k_attn(const __hip_bfloat16* __restrict__ Qp,
    const __hip_bfloat16* __restrict__ Kp, const __hip_bfloat16* __restrict__ Vt,
    __hip_bfloat16* __restrict__ Ob) {
  __shared__ alignas(16) __hip_bfloat16 lK[2][64 * 32];   // 4KB each
  __shared__ alignas(16) __hip_bfloat16 lV[2][32 * 64];   // 4KB each
  const int lin = blockIdx.x;           // 0..1023
  const int xcd = lin & 7;
  const int idx = lin >> 3;             // 0..127
  const int h = xcd * 2 + (idx & 1);    // 2 heads per XCD
  const int qb = 63 - (idx >> 1);       // DESCENDING: big blocks first (LPT)
  const int nt = qb + 1;
  const int tid = threadIdx.x;
  const int lane = tid & 63, w = tid >> 6;
  const int g = lane >> 4, c = lane & 15;
  // staging source mapping (inverse of the LDS read permutation)
  const int krow = (tid >> 6) * 16 + (tid & 15);           // kv row within tile
  const int kcol = ((tid >> 4) & 3) * 8;                   // dim slot
  const int vrow = ((tid >> 6) & 1) * 16 + (tid & 15);     // d row
  const int vcol = ((tid >> 7) & 1) * 32 + ((tid >> 4) & 3) * 8;  // kv slot within tile
  const __hip_bfloat16* Kh = Kp + (size_t)h * TT * 32 + (size_t)krow * 32 + kcol;
  const __hip_bfloat16* Vh = Vt + (size_t)h * 32 * TT + (size_t)vrow * TT + vcol;
  const f32x4 zz = {0.f, 0.f, 0.f, 0.f};
  // pi-permuted V base byte offset within a buffer: chunk kv=4g of d-row c
  const int vb0 = (g >> 1) * 256 + c * 16 + 8 * (g & 1);

  const int qrow = qb * 64 + w * 16 + c;
  const short8 qf =
      *reinterpret_cast<const short8*>(Qp + ((size_t)h * TT + qrow) * 32 + 8 * g);
  f32x4 o0 = zz, o1 = zz;
  float mst = -1e30f, lsum = 0.f;
  int cur = 0;
  // prologue: stage tile 0 into buf 0
  __builtin_amdgcn_global_load_lds(
      (const __attribute__((address_space(1))) void*)Kh,
      (__attribute__((address_space(3))) void*)(lK[0] + tid * 8), 16, 0, 0);
  __builtin_amdgcn_global_load_lds(
      (const __attribute__((address_space(1))) void*)Vh,
      (__attribute__((address_space(3))) void*)(lV[0] + tid * 8), 16, 0, 0);

  for (int it = 0; it < nt; ++it) {
    __syncthreads();  // buf[cur] staged + all waves done with buf[cur^1]
    if (it + 1 < nt) {
      const int kv1 = (it + 1) * 64;
      __builtin_amdgcn_global_load_lds(
          (const __attribute__((address_space(1))) void*)(Kh + (size_t)kv1 * 32),
          (__attribute__((address_space(3))) void*)(lK[cur ^ 1] + tid * 8), 16, 0, 0);
      __builtin_amdgcn_global_load_lds(
          (const __attribute__((address_space(1))) void*)(Vh + kv1),
          (__attribute__((address_space(3))) void*)(lV[cur ^ 1] + tid * 8), 16, 0, 0);
    }
    // K fragments: addr = base + lane*16 (conflict-free)
    const char* kb = (const char*)lK[cur];
    short8 kf[4];
#pragma unroll
    for (int ct = 0; ct < 4; ++ct)
      kf[ct] = *reinterpret_cast<const short8*>(kb + ct * 1024 + lane * 16);
    // V fragments, pi-permuted: two b64 chunks per MFMA operand
    const char* vb = (const char*)lV[cur];
    union U8 { unsigned u[4]; short8 v8; };
    U8 aA0, aA1, aB0, aB1;
    *reinterpret_cast<uint2*>(&aA0.u[0]) = *reinterpret_cast<const uint2*>(vb + vb0);
    *reinterpret_cast<uint2*>(&aA0.u[2]) = *reinterpret_cast<const uint2*>(vb + vb0 + 512);
    *reinterpret_cast<uint2*>(&aB0.u[0]) = *reinterpret_cast<const uint2*>(vb + vb0 + 1024);
    *reinterpret_cast<uint2*>(&aB0.u[2]) = *reinterpret_cast<const uint2*>(vb + vb0 + 1536);
    *reinterpret_cast<uint2*>(&aA1.u[0]) = *reinterpret_cast<const uint2*>(vb + vb0 + 2048);
    *reinterpret_cast<uint2*>(&aA1.u[2]) = *reinterpret_cast<const uint2*>(vb + vb0 + 2560);
    *reinterpret_cast<uint2*>(&aB1.u[0]) = *reinterpret_cast<const uint2*>(vb + vb0 + 3072);
    *reinterpret_cast<uint2*>(&aB1.u[2]) = *reinterpret_cast<const uint2*>(vb + vb0 + 3584);
    f32x4 s[4];
#pragma unroll
    for (int ct = 0; ct < 4; ++ct)
      s[ct] = __builtin_amdgcn_mfma_f32_16x16x32_bf16(kf[ct], qf, zz, 0, 0, 0);  // swapped
    if (it == nt - 1) {  // diagonal tile: mask k > q
#pragma unroll
      for (int ct = 0; ct < 4; ++ct)
#pragma unroll
        for (int j = 0; j < 4; ++j)
          if (ct * 16 + g * 4 + j > w * 16 + c) s[ct][j] = -1e30f;
    }
    // in-lane max over 16 scores
    float m01 = fmaxf(fmaxf(s[0][0], s[0][1]), fmaxf(s[0][2], s[0][3]));
    float m23 = fmaxf(fmaxf(s[1][0], s[1][1]), fmaxf(s[1][2], s[1][3]));
    float m45 = fmaxf(fmaxf(s[2][0], s[2][1]), fmaxf(s[2][2], s[2][3]));
    float m67 = fmaxf(fmaxf(s[3][0], s[3][1]), fmaxf(s[3][2], s[3][3]));
    float pm_ = fmaxf(fmaxf(m01, m23), fmaxf(m45, m67));
    if (__any(pm_ > mst + 8.0f)) {  // defer-max
      float pm2 = fmaxf(pm_, __shfl_xor(pm_, 16, 64));
      pm2 = fmaxf(pm2, __shfl_xor(pm2, 32, 64));
      const float nm = fmaxf(mst, pm2);
      const float alpha = exp2f(mst - nm);
      mst = nm;
      lsum *= alpha;
#pragma unroll
      for (int j = 0; j < 4; ++j) { o0[j] *= alpha; o1[j] *= alpha; }
    }
    float ts = 0.f;
#pragma unroll
    for (int ct = 0; ct < 4; ++ct) {
#pragma unroll
      for (int j = 0; j < 4; ++j) s[ct][j] = exp2f(s[ct][j] - mst);
      ts += (s[ct][0] + s[ct][1]) + (s[ct][2] + s[ct][3]);
    }
    lsum += ts;
    // pack P to bf16 IN-LANE (pi permutation: B-frag = own values, no LDS)
    union U8 pb0, pb1;
    pb0.u[0] = pk2(s[0][0], s[0][1]);
    pb0.u[1] = pk2(s[0][2], s[0][3]);
    pb0.u[2] = pk2(s[1][0], s[1][1]);
    pb0.u[3] = pk2(s[1][2], s[1][3]);
    pb1.u[0] = pk2(s[2][0], s[2][1]);
    pb1.u[1] = pk2(s[2][2], s[2][3]);
    pb1.u[2] = pk2(s[3][0], s[3][1]);
    pb1.u[3] = pk2(s[3][2], s[3][3]);
    // O^T accumulate: C col = q-row = lane c (same layout as before)
    o0 = __builtin_amdgcn_mfma_f32_16x16x32_bf16(aA0.v8, pb0.v8, o0, 0, 0, 0);
    o0 = __builtin_amdgcn_mfma_f32_16x16x32_bf16(aA1.v8, pb1.v8, o0, 0, 0, 0);
    o1 = __builtin_amdgcn_mfma_f32_16x16x32_bf16(aB0.v8, pb0.v8, o1, 0, 0, 0);
    o1 = __builtin_amdgcn_mfma_f32_16x16x32_bf16(aB1.v8, pb1.v8, o1, 0, 0, 0);
    cur ^= 1;
  }
  // final lsum reduce across g-lanes of row c; write Ob
  lsum += __shfl_xor(lsum, 16, 64);
  lsum += __shfl_xor(lsum, 32, 64);
  const float inv = 1.0f / lsum;
  __hip_bfloat16* dst = Ob + (size_t)qrow * DATTN + h * 32;
  short4v w0, w1;
#pragma unroll
  for (int j = 0; j < 4; ++j) { w0[j] = f2bf(o0[j] * inv); w1[j] = f2bf(o1[j] * inv); }
  *reinterpret_cast<short4v*>(dst + g * 4) = w0;
  *reinterpret_cast<short4v*>(dst + 16 + g * 4) = w1;
}

extern "C" void kernel_launch(void* const* d_in, const int* in_sizes, int n_in,
                              void* d_out, int out_size, void* d_ws, size_t ws_size,
                              hipStream_t stream) {
  const float* x   = (const float*)d_in[0];
  const float* qsw = (const float*)d_in[1];
  const float* ksw = (const float*)d_in[2];
  const float* qgw = (const float*)d_in[3];
  const float* kgw = (const float*)d_in[4];
  const float* vw  = (const float*)d_in[5];
  const float* ow  = (const float*)d_in[6];
  const float* ls  = (const float*)d_in[7];
  const int* posp  = (const int*)d_in[9];

  size_t off = 0;
  auto alloc = [&](size_t bytes) {
    char* p = (char*)d_ws + off;
    off += (bytes + 255) & ~(size_t)255;
    return (void*)p;
  };
  __hip_bfloat16* Xbf  = (__hip_bfloat16*)alloc((size_t)TT * DM * 2);
  __hip_bfloat16* Wcat = (__hip_bfloat16*)alloc((size_t)NPROJ * DM * 2);
  __hip_bfloat16* OW   = (__hip_bfloat16*)alloc((size_t)DM * DATTN * 2);
  __hip_bfloat16* proj = (__hip_bfloat16*)alloc((size_t)TT * NPROJ * 2);
  __hip_bfloat16* Qp   = (__hip_bfloat16*)alloc((size_t)NH * TT * 32 * 2);
  __hip_bfloat16* Kpk  = (__hip_bfloat16*)alloc((size_t)NH * TT * 32 * 2);
  __hip_bfloat16* Vt   = (__hip_bfloat16*)alloc((size_t)NH * 32 * TT * 2);
  __hip_bfloat16* Ob   = (__hip_bfloat16*)alloc((size_t)TT * DATTN * 2);

  k_f32_to_bf16<<<dim3((TT * DM / 4) / 256), 256, 0, stream>>>(x, Xbf, TT * DM / 4);
  k_f32_to_bf16<<<dim3((DM * DATTN / 4) / 256), 256, 0, stream>>>(ow, OW, DM * DATTN / 4);
  k_pack_wcat<<<dim3((NPROJ * DM / 4) / 256), 256, 0, stream>>>(qsw, ksw, qgw, kgw, vw, Wcat,
                                                                NPROJ * DM / 4);
  k_gemm_bt<1><<<dim3(TT / 128, NPROJ / 128), 256, 0, stream>>>(Xbf, Wcat, (void*)proj,
                                                                TT, NPROJ, DM);
  k_rope_pack<<<dim3(TT * NH / 256), 256, 0, stream>>>(proj, ls, posp, Qp, Kpk, Vt);
  k_attn<<<dim3(1024), 256, 0, stream>>>(Qp, Kpk, Vt, Ob);
  k_gemm_bt<0><<<dim3(TT / 128, DM / 128), 256, 0, stream>>>(Ob, OW, (void*)d_out,
                                                             TT, DM, DATTN);
}

// Round 14
// 125.757 us; speedup vs baseline: 1.0805x; 1.0624x over previous
//
#include <hip/hip_runtime.h>
#include <hip/hip_bf16.h>

typedef __attribute__((ext_vector_type(8))) short short8;
typedef __attribute__((ext_vector_type(4))) short short4v;
typedef __attribute__((ext_vector_type(4))) float f32x4;

#define TT 4096
#define DM 1024
#define NH 16
#define NPROJ 1280   // 128 qs + 128 ks + 256 qg + 256 kg + 512 v
#define DATTN 512

static __device__ __forceinline__ short f2bf(float f) {
  __hip_bfloat16 h = __float2bfloat16(f);
  return *reinterpret_cast<short*>(&h);
}
static __device__ __forceinline__ float bf2f(__hip_bfloat16 h) { return __bfloat162float(h); }

// ---------------- fp32 -> bf16 convert (x, out_w) ----------------
__global__ __launch_bounds__(256) void k_f32_to_bf16(const float* __restrict__ in,
                                                     __hip_bfloat16* __restrict__ out, int n4) {
  int i = blockIdx.x * blockDim.x + threadIdx.x;
  if (i >= n4) return;
  float4 v = reinterpret_cast<const float4*>(in)[i];
  short4v o;
  o[0] = f2bf(v.x); o[1] = f2bf(v.y); o[2] = f2bf(v.z); o[3] = f2bf(v.w);
  reinterpret_cast<short4v*>(out)[i] = o;
}

// ---------------- concat 5 weight matrices into (1280,1024) bf16 ----------------
__global__ __launch_bounds__(256) void k_pack_wcat(const float* __restrict__ qs,
    const float* __restrict__ ks, const float* __restrict__ qg, const float* __restrict__ kg,
    const float* __restrict__ vw, __hip_bfloat16* __restrict__ w, int n4) {
  int i = blockIdx.x * blockDim.x + threadIdx.x;
  if (i >= n4) return;
  int idx = i * 4;
  int row = idx >> 10;
  int col = idx & 1023;
  const float* src;
  if (row < 128)      src = qs + (size_t)row * DM;
  else if (row < 256) src = ks + (size_t)(row - 128) * DM;
  else if (row < 512) src = qg + (size_t)(row - 256) * DM;
  else if (row < 768) src = kg + (size_t)(row - 512) * DM;
  else                src = vw + (size_t)(row - 768) * DM;
  float4 v = *reinterpret_cast<const float4*>(src + col);
  short4v o;
  o[0] = f2bf(v.x); o[1] = f2bf(v.y); o[2] = f2bf(v.z); o[3] = f2bf(v.w);
  *reinterpret_cast<short4v*>(w + idx) = o;
}

// ---------------- bf16 GEMM, B^T layout, BM=64 BN=128 BK=32 ----------------
// Grid (M/64, N/128): proj = 640 blocks (2.5/CU), out = 512 (2/CU) — doubles
// co-residency vs 128x128 so stage/compute overlaps across blocks (m114).
// 4 waves: wave (wid>>1, wid&1) computes 32x64; acc[2][4] of 16x16 frags.
template<int OUT_BF16>
__global__ __launch_bounds__(256) void k_gemm_bt(const __hip_bfloat16* __restrict__ A,
    const __hip_bfloat16* __restrict__ B, void* __restrict__ Cv, int M, int N, int K) {
  __shared__ alignas(16) __hip_bfloat16 lA[64 * 32];
  __shared__ alignas(16) __hip_bfloat16 lB[128 * 32];
  const int tid = threadIdx.x;
  const int lane = tid & 63;
  const int wid = tid >> 6;
  const int m0 = blockIdx.x * 64, n0 = blockIdx.y * 128;
  const int wm = (wid >> 1) * 32, wn = (wid & 1) * 64;
  const int srow = tid >> 2;          // 0..63
  const int scol = (tid & 3) * 8;     // bf16 elements
  const int fr = lane & 15, fk = (lane >> 4) * 8;
  f32x4 acc[2][4];
  const f32x4 zz = {0.f, 0.f, 0.f, 0.f};
#pragma unroll
  for (int m = 0; m < 2; ++m)
#pragma unroll
    for (int n = 0; n < 4; ++n) acc[m][n] = zz;

  for (int kt = 0; kt < K; kt += 32) {
    __syncthreads();
    {
      const __hip_bfloat16* ga0 = A + (size_t)(m0 + srow) * K + kt + scol;
      const __hip_bfloat16* gb0 = B + (size_t)(n0 + srow) * K + kt + scol;
      const __hip_bfloat16* gb1 = B + (size_t)(n0 + 64 + srow) * K + kt + scol;
      __builtin_amdgcn_global_load_lds((const __attribute__((address_space(1))) void*)ga0,
          (__attribute__((address_space(3))) void*)(lA + srow * 32 + scol), 16, 0, 0);
      __builtin_amdgcn_global_load_lds((const __attribute__((address_space(1))) void*)gb0,
          (__attribute__((address_space(3))) void*)(lB + srow * 32 + scol), 16, 0, 0);
      __builtin_amdgcn_global_load_lds((const __attribute__((address_space(1))) void*)gb1,
          (__attribute__((address_space(3))) void*)(lB + (64 + srow) * 32 + scol), 16, 0, 0);
    }
    __syncthreads();
    short8 af[2], bfr[4];
#pragma unroll
    for (int m = 0; m < 2; ++m)
      af[m] = *reinterpret_cast<const short8*>(lA + (wm + m * 16 + fr) * 32 + fk);
#pragma unroll
    for (int n = 0; n < 4; ++n)
      bfr[n] = *reinterpret_cast<const short8*>(lB + (wn + n * 16 + fr) * 32 + fk);
#pragma unroll
    for (int m = 0; m < 2; ++m)
#pragma unroll
      for (int n = 0; n < 4; ++n)
        acc[m][n] = __builtin_amdgcn_mfma_f32_16x16x32_bf16(af[m], bfr[n], acc[m][n], 0, 0, 0);
  }
  const int cr = (lane >> 4) * 4, cc = lane & 15;
#pragma unroll
  for (int m = 0; m < 2; ++m)
#pragma unroll
    for (int n = 0; n < 4; ++n)
#pragma unroll
      for (int j = 0; j < 4; ++j) {
        const int row = m0 + wm + m * 16 + cr + j;
        const int col = n0 + wn + n * 16 + cc;
        if (OUT_BF16)
          ((__hip_bfloat16*)Cv)[(size_t)row * N + col] = __float2bfloat16(acc[m][n][j]);
        else
          ((float*)Cv)[(size_t)row * N + col] = acc[m][n][j];
      }
}

// ---------------- RoPE + pack Q/K (H,T,32) and V^T (H,32,T) ----------------
// qscale folds 1/sqrt(24) * exp(logit_scale) * log2(e)  (softmax uses exp2)
__global__ __launch_bounds__(256) void k_rope_pack(const __hip_bfloat16* __restrict__ proj,
    const float* __restrict__ ls, const int* __restrict__ posp,
    __hip_bfloat16* __restrict__ Qp, __hip_bfloat16* __restrict__ Kp,
    __hip_bfloat16* __restrict__ Vt) {
  const int gid = blockIdx.x * blockDim.x + threadIdx.x;  // T*NH, t fastest
  const int t = gid & (TT - 1);
  const int h = gid >> 12;
  const __hip_bfloat16* pr = proj + (size_t)t * NPROJ;
  const float qscale = 0.20412414523193154f * 1.4426950408889634f * __expf(ls[h]);
  const float pos = (float)(t + posp[0]);
  const float invf[8] = {1.0f, 0.31622776601683794f, 0.1f, 0.031622776601683794f,
                         0.01f, 0.0031622776601683794f, 0.001f, 0.00031622776601683794f};
  short8 qv[4], kv[4];
  const short8 z8 = {0, 0, 0, 0, 0, 0, 0, 0};
  qv[3] = z8; kv[3] = z8;
#pragma unroll
  for (int i = 0; i < 8; ++i) {
    qv[0][i] = f2bf(bf2f(pr[h * 8 + i]) * qscale);
    kv[0][i] = f2bf(bf2f(pr[128 + h * 8 + i]));
  }
#pragma unroll
  for (int i = 0; i < 8; ++i) {
    const float ang = pos * invf[i];
    float ss, cc;
    __sincosf(ang, &ss, &cc);
    const float x1q = bf2f(pr[256 + h * 16 + i]), x2q = bf2f(pr[256 + h * 16 + 8 + i]);
    const float x1k = bf2f(pr[512 + h * 16 + i]), x2k = bf2f(pr[512 + h * 16 + 8 + i]);
    qv[1][i] = f2bf((x1q * cc - x2q * ss) * qscale);
    qv[2][i] = f2bf((x1q * ss + x2q * cc) * qscale);
    kv[1][i] = f2bf(x1k * cc - x2k * ss);
    kv[2][i] = f2bf(x1k * ss + x2k * cc);
  }
  short8* qdst = reinterpret_cast<short8*>(Qp + ((size_t)h * TT + t) * 32);
  short8* kdst = reinterpret_cast<short8*>(Kp + ((size_t)h * TT + t) * 32);
#pragma unroll
  for (int p = 0; p < 4; ++p) { qdst[p] = qv[p]; kdst[p] = kv[p]; }
#pragma unroll
  for (int i = 0; i < 32; ++i)
    Vt[((size_t)h * 32 + i) * TT + t] = pr[768 + h * 32 + i];
}

// ---------------- causal flash attention (R11: LDS K/V, LPT, 4 blocks/CU) -------------
__global__ __launch_bounds__(256) void k_attn(const __hip_bfloat16* __restrict__ Qp,
    const __hip_bfloat16* __restrict__ Kp, const __hip_bfloat16* __restrict__ Vt,
    __hip_bfloat16* __restrict__ Ob) {
  __shared__ alignas(16) __hip_bfloat16 lK[2][64 * 32];   // 4KB each
  __shared__ alignas(16) __hip_bfloat16 lV[2][32 * 64];   // 4KB each
  __shared__ alignas(16) __hip_bfloat16 Plds[4][16][72];
  const int lin = blockIdx.x;           // 0..1023
  const int xcd = lin & 7;
  const int idx = lin >> 3;             // 0..127
  const int h = xcd * 2 + (idx & 1);    // 2 heads per XCD
  const int qb = 63 - (idx >> 1);       // DESCENDING: big blocks first (LPT)
  const int nt = qb + 1;
  const int tid = threadIdx.x;
  const int lane = tid & 63, w = tid >> 6;
  const int g = lane >> 4, c = lane & 15;
  // staging source mapping (inverse of the LDS read permutation)
  const int krow = (tid >> 6) * 16 + (tid & 15);           // kv row within tile
  const int kcol = ((tid >> 4) & 3) * 8;                   // dim slot
  const int vrow = ((tid >> 6) & 1) * 16 + (tid & 15);     // d row
  const int vcol = ((tid >> 7) & 1) * 32 + ((tid >> 4) & 3) * 8;  // kv slot within tile
  const __hip_bfloat16* Kh = Kp + (size_t)h * TT * 32 + (size_t)krow * 32 + kcol;
  const __hip_bfloat16* Vh = Vt + (size_t)h * 32 * TT + (size_t)vrow * TT + vcol;
  const f32x4 zz = {0.f, 0.f, 0.f, 0.f};

  const int qrow = qb * 64 + w * 16 + c;
  const short8 qf =
      *reinterpret_cast<const short8*>(Qp + ((size_t)h * TT + qrow) * 32 + 8 * g);
  f32x4 o0 = zz, o1 = zz;
  float mst = -1e30f, lsum = 0.f;
  int cur = 0;
  // prologue: stage tile 0 into buf 0
  __builtin_amdgcn_global_load_lds(
      (const __attribute__((address_space(1))) void*)Kh,
      (__attribute__((address_space(3))) void*)(lK[0] + tid * 8), 16, 0, 0);
  __builtin_amdgcn_global_load_lds(
      (const __attribute__((address_space(1))) void*)Vh,
      (__attribute__((address_space(3))) void*)(lV[0] + tid * 8), 16, 0, 0);

  for (int it = 0; it < nt; ++it) {
    __syncthreads();  // buf[cur] staged + all waves done with buf[cur^1]
    if (it + 1 < nt) {
      const int kv1 = (it + 1) * 64;
      __builtin_amdgcn_global_load_lds(
          (const __attribute__((address_space(1))) void*)(Kh + (size_t)kv1 * 32),
          (__attribute__((address_space(3))) void*)(lK[cur ^ 1] + tid * 8), 16, 0, 0);
      __builtin_amdgcn_global_load_lds(
          (const __attribute__((address_space(1))) void*)(Vh + kv1),
          (__attribute__((address_space(3))) void*)(lV[cur ^ 1] + tid * 8), 16, 0, 0);
    }
    // K fragments: addr = base + lane*16 (conflict-free)
    const char* kb = (const char*)lK[cur];
    short8 kf[4];
#pragma unroll
    for (int ct = 0; ct < 4; ++ct)
      kf[ct] = *reinterpret_cast<const short8*>(kb + ct * 1024 + lane * 16);
    // V fragments: addr = base + lane*16 (conflict-free)
    const char* vb = (const char*)lV[cur];
    const short8 v00 = *reinterpret_cast<const short8*>(vb + lane * 16);
    const short8 v10 = *reinterpret_cast<const short8*>(vb + 1024 + lane * 16);
    const short8 v01 = *reinterpret_cast<const short8*>(vb + 2048 + lane * 16);
    const short8 v11 = *reinterpret_cast<const short8*>(vb + 3072 + lane * 16);
    f32x4 s[4];
#pragma unroll
    for (int ct = 0; ct < 4; ++ct)
      s[ct] = __builtin_amdgcn_mfma_f32_16x16x32_bf16(kf[ct], qf, zz, 0, 0, 0);  // swapped
    if (it == nt - 1) {  // diagonal tile: mask k > q
#pragma unroll
      for (int ct = 0; ct < 4; ++ct)
#pragma unroll
        for (int j = 0; j < 4; ++j)
          if (ct * 16 + g * 4 + j > w * 16 + c) s[ct][j] = -1e30f;
    }
    // in-lane max over 16 scores
    float m01 = fmaxf(fmaxf(s[0][0], s[0][1]), fmaxf(s[0][2], s[0][3]));
    float m23 = fmaxf(fmaxf(s[1][0], s[1][1]), fmaxf(s[1][2], s[1][3]));
    float m45 = fmaxf(fmaxf(s[2][0], s[2][1]), fmaxf(s[2][2], s[2][3]));
    float m67 = fmaxf(fmaxf(s[3][0], s[3][1]), fmaxf(s[3][2], s[3][3]));
    float pm_ = fmaxf(fmaxf(m01, m23), fmaxf(m45, m67));
    if (__any(pm_ > mst + 8.0f)) {  // defer-max
      float pm2 = fmaxf(pm_, __shfl_xor(pm_, 16, 64));
      pm2 = fmaxf(pm2, __shfl_xor(pm2, 32, 64));
      const float nm = fmaxf(mst, pm2);
      const float alpha = exp2f(mst - nm);
      mst = nm;
      lsum *= alpha;
#pragma unroll
      for (int j = 0; j < 4; ++j) { o0[j] *= alpha; o1[j] *= alpha; }
    }
    float ts = 0.f;
#pragma unroll
    for (int ct = 0; ct < 4; ++ct) {
#pragma unroll
      for (int j = 0; j < 4; ++j) s[ct][j] = exp2f(s[ct][j] - mst);
      ts += (s[ct][0] + s[ct][1]) + (s[ct][2] + s[ct][3]);
    }
    lsum += ts;
    // P -> LDS (packed bf16 pairs), per-wave private slice (2-way max: free)
#pragma unroll
    for (int ct = 0; ct < 4; ++ct) {
      float2 p01; p01.x = s[ct][0]; p01.y = s[ct][1];
      float2 p23; p23.x = s[ct][2]; p23.y = s[ct][3];
      __hip_bfloat162 b01 = __float22bfloat162_rn(p01);
      __hip_bfloat162 b23 = __float22bfloat162_rn(p23);
      *reinterpret_cast<__hip_bfloat162*>(&Plds[w][c][ct * 16 + g * 4]) = b01;
      *reinterpret_cast<__hip_bfloat162*>(&Plds[w][c][ct * 16 + g * 4 + 2]) = b23;
    }
    const short8 pf0 = *reinterpret_cast<const short8*>(&Plds[w][c][8 * g]);
    const short8 pf1 = *reinterpret_cast<const short8*>(&Plds[w][c][32 + 8 * g]);
    // O^T: C col = q-row = lane c
    o0 = __builtin_amdgcn_mfma_f32_16x16x32_bf16(v00, pf0, o0, 0, 0, 0);
    o0 = __builtin_amdgcn_mfma_f32_16x16x32_bf16(v01, pf1, o0, 0, 0, 0);
    o1 = __builtin_amdgcn_mfma_f32_16x16x32_bf16(v10, pf0, o1, 0, 0, 0);
    o1 = __builtin_amdgcn_mfma_f32_16x16x32_bf16(v11, pf1, o1, 0, 0, 0);
    cur ^= 1;
  }
  // final lsum reduce across g-lanes of row c; write Ob
  lsum += __shfl_xor(lsum, 16, 64);
  lsum += __shfl_xor(lsum, 32, 64);
  const float inv = 1.0f / lsum;
  __hip_bfloat16* dst = Ob + (size_t)qrow * DATTN + h * 32;
  short4v w0, w1;
#pragma unroll
  for (int j = 0; j < 4; ++j) { w0[j] = f2bf(o0[j] * inv); w1[j] = f2bf(o1[j] * inv); }
  *reinterpret_cast<short4v*>(dst + g * 4) = w0;
  *reinterpret_cast<short4v*>(dst + 16 + g * 4) = w1;
}

extern "C" void kernel_launch(void* const* d_in, const int* in_sizes, int n_in,
                              void* d_out, int out_size, void* d_ws, size_t ws_size,
                              hipStream_t stream) {
  const float* x   = (const float*)d_in[0];
  const float* qsw = (const float*)d_in[1];
  const float* ksw = (const float*)d_in[2];
  const float* qgw = (const float*)d_in[3];
  const float* kgw = (const float*)d_in[4];
  const float* vw  = (const float*)d_in[5];
  const float* ow  = (const float*)d_in[6];
  const float* ls  = (const float*)d_in[7];
  const int* posp  = (const int*)d_in[9];

  size_t off = 0;
  auto alloc = [&](size_t bytes) {
    char* p = (char*)d_ws + off;
    off += (bytes + 255) & ~(size_t)255;
    return (void*)p;
  };
  __hip_bfloat16* Xbf  = (__hip_bfloat16*)alloc((size_t)TT * DM * 2);
  __hip_bfloat16* Wcat = (__hip_bfloat16*)alloc((size_t)NPROJ * DM * 2);
  __hip_bfloat16* OW   = (__hip_bfloat16*)alloc((size_t)DM * DATTN * 2);
  __hip_bfloat16* proj = (__hip_bfloat16*)alloc((size_t)TT * NPROJ * 2);
  __hip_bfloat16* Qp   = (__hip_bfloat16*)alloc((size_t)NH * TT * 32 * 2);
  __hip_bfloat16* Kpk  = (__hip_bfloat16*)alloc((size_t)NH * TT * 32 * 2);
  __hip_bfloat16* Vt   = (__hip_bfloat16*)alloc((size_t)NH * 32 * TT * 2);
  __hip_bfloat16* Ob   = (__hip_bfloat16*)alloc((size_t)TT * DATTN * 2);

  k_f32_to_bf16<<<dim3((TT * DM / 4) / 256), 256, 0, stream>>>(x, Xbf, TT * DM / 4);
  k_f32_to_bf16<<<dim3((DM * DATTN / 4) / 256), 256, 0, stream>>>(ow, OW, DM * DATTN / 4);
  k_pack_wcat<<<dim3((NPROJ * DM / 4) / 256), 256, 0, stream>>>(qsw, ksw, qgw, kgw, vw, Wcat,
                                                                NPROJ * DM / 4);
  k_gemm_bt<1><<<dim3(TT / 64, NPROJ / 128), 256, 0, stream>>>(Xbf, Wcat, (void*)proj,
                                                               TT, NPROJ, DM);
  k_rope_pack<<<dim3(TT * NH / 256), 256, 0, stream>>>(proj, ls, posp, Qp, Kpk, Vt);
  k_attn<<<dim3(1024), 256, 0, stream>>>(Qp, Kpk, Vt, Ob);
  k_gemm_bt<0><<<dim3(TT / 64, DM / 128), 256, 0, stream>>>(Ob, OW, (void*)d_out,
                                                            TT, DM, DATTN);
}

// Round 15
// 122.253 us; speedup vs baseline: 1.1114x; 1.0287x over previous
//
#include <hip/hip_runtime.h>
#include <hip/hip_bf16.h>

typedef __attribute__((ext_vector_type(8))) short short8;
typedef __attribute__((ext_vector_type(4))) short short4v;
typedef __attribute__((ext_vector_type(4))) float f32x4;

#define TT 4096
#define DM 1024
#define NH 16
#define NPROJ 1280   // 128 qs + 128 ks + 256 qg + 256 kg + 512 v
#define DATTN 512

static __device__ __forceinline__ short f2bf(float f) {
  __hip_bfloat16 h = __float2bfloat16(f);
  return *reinterpret_cast<short*>(&h);
}
static __device__ __forceinline__ float bf2f(__hip_bfloat16 h) { return __bfloat162float(h); }
static __device__ __forceinline__ float bfs2f(short s) {
  __hip_bfloat16 h = *reinterpret_cast<__hip_bfloat16*>(&s);
  return __bfloat162float(h);
}

// ---------------- fused prep: x->bf16, ow->bf16, wcat concat (one launch) ----------------
// blocks [0, NB_X): x conv; [NB_X, NB_X+NB_OW): ow conv; rest: wcat.
#define NB_X   (TT * DM / 4 / 256)        // 4096 blocks
#define NB_OW  (DM * DATTN / 4 / 256)     // 512 blocks
#define NB_WC  (NPROJ * DM / 4 / 256)     // 1280 blocks
__global__ __launch_bounds__(256) void k_prep(const float* __restrict__ x,
    const float* __restrict__ ow, const float* __restrict__ qs, const float* __restrict__ ks,
    const float* __restrict__ qg, const float* __restrict__ kg, const float* __restrict__ vw,
    __hip_bfloat16* __restrict__ Xbf, __hip_bfloat16* __restrict__ OW,
    __hip_bfloat16* __restrict__ Wcat) {
  const int b = blockIdx.x;
  if (b < NB_X) {
    const int i = b * 256 + threadIdx.x;
    float4 v = reinterpret_cast<const float4*>(x)[i];
    short4v o;
    o[0] = f2bf(v.x); o[1] = f2bf(v.y); o[2] = f2bf(v.z); o[3] = f2bf(v.w);
    reinterpret_cast<short4v*>(Xbf)[i] = o;
  } else if (b < NB_X + NB_OW) {
    const int i = (b - NB_X) * 256 + threadIdx.x;
    float4 v = reinterpret_cast<const float4*>(ow)[i];
    short4v o;
    o[0] = f2bf(v.x); o[1] = f2bf(v.y); o[2] = f2bf(v.z); o[3] = f2bf(v.w);
    reinterpret_cast<short4v*>(OW)[i] = o;
  } else {
    const int i = (b - NB_X - NB_OW) * 256 + threadIdx.x;
    const int idx = i * 4;
    const int row = idx >> 10;
    const int col = idx & 1023;
    const float* src;
    if (row < 128)      src = qs + (size_t)row * DM;
    else if (row < 256) src = ks + (size_t)(row - 128) * DM;
    else if (row < 512) src = qg + (size_t)(row - 256) * DM;
    else if (row < 768) src = kg + (size_t)(row - 512) * DM;
    else                src = vw + (size_t)(row - 768) * DM;
    float4 v = *reinterpret_cast<const float4*>(src + col);
    short4v o;
    o[0] = f2bf(v.x); o[1] = f2bf(v.y); o[2] = f2bf(v.z); o[3] = f2bf(v.w);
    *reinterpret_cast<short4v*>(Wcat + idx) = o;
  }
}

// ---------------- bf16 GEMM, B^T layout, BM=64 BN=128 BK=32 ----------------
template<int OUT_BF16>
__global__ __launch_bounds__(256) void k_gemm_bt(const __hip_bfloat16* __restrict__ A,
    const __hip_bfloat16* __restrict__ B, void* __restrict__ Cv, int M, int N, int K) {
  __shared__ alignas(16) __hip_bfloat16 lA[64 * 32];
  __shared__ alignas(16) __hip_bfloat16 lB[128 * 32];
  const int tid = threadIdx.x;
  const int lane = tid & 63;
  const int wid = tid >> 6;
  const int m0 = blockIdx.x * 64, n0 = blockIdx.y * 128;
  const int wm = (wid >> 1) * 32, wn = (wid & 1) * 64;
  const int srow = tid >> 2;          // 0..63
  const int scol = (tid & 3) * 8;     // bf16 elements
  const int fr = lane & 15, fk = (lane >> 4) * 8;
  f32x4 acc[2][4];
  const f32x4 zz = {0.f, 0.f, 0.f, 0.f};
#pragma unroll
  for (int m = 0; m < 2; ++m)
#pragma unroll
    for (int n = 0; n < 4; ++n) acc[m][n] = zz;

  for (int kt = 0; kt < K; kt += 32) {
    __syncthreads();
    {
      const __hip_bfloat16* ga0 = A + (size_t)(m0 + srow) * K + kt + scol;
      const __hip_bfloat16* gb0 = B + (size_t)(n0 + srow) * K + kt + scol;
      const __hip_bfloat16* gb1 = B + (size_t)(n0 + 64 + srow) * K + kt + scol;
      __builtin_amdgcn_global_load_lds((const __attribute__((address_space(1))) void*)ga0,
          (__attribute__((address_space(3))) void*)(lA + srow * 32 + scol), 16, 0, 0);
      __builtin_amdgcn_global_load_lds((const __attribute__((address_space(1))) void*)gb0,
          (__attribute__((address_space(3))) void*)(lB + srow * 32 + scol), 16, 0, 0);
      __builtin_amdgcn_global_load_lds((const __attribute__((address_space(1))) void*)gb1,
          (__attribute__((address_space(3))) void*)(lB + (64 + srow) * 32 + scol), 16, 0, 0);
    }
    __syncthreads();
    short8 af[2], bfr[4];
#pragma unroll
    for (int m = 0; m < 2; ++m)
      af[m] = *reinterpret_cast<const short8*>(lA + (wm + m * 16 + fr) * 32 + fk);
#pragma unroll
    for (int n = 0; n < 4; ++n)
      bfr[n] = *reinterpret_cast<const short8*>(lB + (wn + n * 16 + fr) * 32 + fk);
#pragma unroll
    for (int m = 0; m < 2; ++m)
#pragma unroll
      for (int n = 0; n < 4; ++n)
        acc[m][n] = __builtin_amdgcn_mfma_f32_16x16x32_bf16(af[m], bfr[n], acc[m][n], 0, 0, 0);
  }
  const int cr = (lane >> 4) * 4, cc = lane & 15;
#pragma unroll
  for (int m = 0; m < 2; ++m)
#pragma unroll
    for (int n = 0; n < 4; ++n)
#pragma unroll
      for (int j = 0; j < 4; ++j) {
        const int row = m0 + wm + m * 16 + cr + j;
        const int col = n0 + wn + n * 16 + cc;
        if (OUT_BF16)
          ((__hip_bfloat16*)Cv)[(size_t)row * N + col] = __float2bfloat16(acc[m][n][j]);
        else
          ((float*)Cv)[(size_t)row * N + col] = acc[m][n][j];
      }
}

// ---------------- RoPE + pack Q/K (H,T,32) and V^T (H,32,T), vectorized loads ----------
// All 5 proj regions for one (h,t) are contiguous 16B-aligned runs: 10 short8 loads.
// qscale folds 1/sqrt(24) * exp(logit_scale) * log2(e)  (softmax uses exp2)
__global__ __launch_bounds__(256) void k_rope_pack(const __hip_bfloat16* __restrict__ proj,
    const float* __restrict__ ls, const int* __restrict__ posp,
    __hip_bfloat16* __restrict__ Qp, __hip_bfloat16* __restrict__ Kp,
    __hip_bfloat16* __restrict__ Vt) {
  const int gid = blockIdx.x * blockDim.x + threadIdx.x;  // T*NH, t fastest
  const int t = gid & (TT - 1);
  const int h = gid >> 12;
  const short8* pr8 = reinterpret_cast<const short8*>(proj + (size_t)t * NPROJ);
  const short8 qs8 = pr8[h];
  const short8 ks8 = pr8[16 + h];
  const short8 qg1 = pr8[32 + 2 * h], qg2 = pr8[33 + 2 * h];
  const short8 kg1 = pr8[64 + 2 * h], kg2 = pr8[65 + 2 * h];
  const short8 vv0 = pr8[96 + 4 * h], vv1 = pr8[97 + 4 * h];
  const short8 vv2 = pr8[98 + 4 * h], vv3 = pr8[99 + 4 * h];
  const float qscale = 0.20412414523193154f * 1.4426950408889634f * __expf(ls[h]);
  const float pos = (float)(t + posp[0]);
  const float invf[8] = {1.0f, 0.31622776601683794f, 0.1f, 0.031622776601683794f,
                         0.01f, 0.0031622776601683794f, 0.001f, 0.00031622776601683794f};
  short8 qv[4], kv[4];
  const short8 z8 = {0, 0, 0, 0, 0, 0, 0, 0};
  qv[3] = z8; kv[3] = z8;
#pragma unroll
  for (int i = 0; i < 8; ++i) {
    qv[0][i] = f2bf(bfs2f(qs8[i]) * qscale);
    kv[0][i] = ks8[i];
  }
#pragma unroll
  for (int i = 0; i < 8; ++i) {
    const float ang = pos * invf[i];
    float ss, cc;
    __sincosf(ang, &ss, &cc);
    const float x1q = bfs2f(qg1[i]), x2q = bfs2f(qg2[i]);
    const float x1k = bfs2f(kg1[i]), x2k = bfs2f(kg2[i]);
    qv[1][i] = f2bf((x1q * cc - x2q * ss) * qscale);
    qv[2][i] = f2bf((x1q * ss + x2q * cc) * qscale);
    kv[1][i] = f2bf(x1k * cc - x2k * ss);
    kv[2][i] = f2bf(x1k * ss + x2k * cc);
  }
  short8* qdst = reinterpret_cast<short8*>(Qp + ((size_t)h * TT + t) * 32);
  short8* kdst = reinterpret_cast<short8*>(Kp + ((size_t)h * TT + t) * 32);
#pragma unroll
  for (int p = 0; p < 4; ++p) { qdst[p] = qv[p]; kdst[p] = kv[p]; }
  __hip_bfloat16* vdst = Vt + (size_t)h * 32 * TT + t;
#pragma unroll
  for (int i = 0; i < 8; ++i) {
    *reinterpret_cast<short*>(vdst + (size_t)i * TT) = vv0[i];
    *reinterpret_cast<short*>(vdst + (size_t)(8 + i) * TT) = vv1[i];
    *reinterpret_cast<short*>(vdst + (size_t)(16 + i) * TT) = vv2[i];
    *reinterpret_cast<short*>(vdst + (size_t)(24 + i) * TT) = vv3[i];
  }
}

// ---------------- causal flash attention (R11: LDS K/V, LPT, 4 blocks/CU) -------------
__global__ __launch_bounds__(256) void k_attn(const __hip_bfloat16* __restrict__ Qp,
    const __hip_bfloat16* __restrict__ Kp, const __hip_bfloat16* __restrict__ Vt,
    __hip_bfloat16* __restrict__ Ob) {
  __shared__ alignas(16) __hip_bfloat16 lK[2][64 * 32];   // 4KB each
  __shared__ alignas(16) __hip_bfloat16 lV[2][32 * 64];   // 4KB each
  __shared__ alignas(16) __hip_bfloat16 Plds[4][16][72];
  const int lin = blockIdx.x;           // 0..1023
  const int xcd = lin & 7;
  const int idx = lin >> 3;             // 0..127
  const int h = xcd * 2 + (idx & 1);    // 2 heads per XCD
  const int qb = 63 - (idx >> 1);       // DESCENDING: big blocks first (LPT)
  const int nt = qb + 1;
  const int tid = threadIdx.x;
  const int lane = tid & 63, w = tid >> 6;
  const int g = lane >> 4, c = lane & 15;
  // staging source mapping (inverse of the LDS read permutation)
  const int krow = (tid >> 6) * 16 + (tid & 15);           // kv row within tile
  const int kcol = ((tid >> 4) & 3) * 8;                   // dim slot
  const int vrow = ((tid >> 6) & 1) * 16 + (tid & 15);     // d row
  const int vcol = ((tid >> 7) & 1) * 32 + ((tid >> 4) & 3) * 8;  // kv slot within tile
  const __hip_bfloat16* Kh = Kp + (size_t)h * TT * 32 + (size_t)krow * 32 + kcol;
  const __hip_bfloat16* Vh = Vt + (size_t)h * 32 * TT + (size_t)vrow * TT + vcol;
  const f32x4 zz = {0.f, 0.f, 0.f, 0.f};

  const int qrow = qb * 64 + w * 16 + c;
  const short8 qf =
      *reinterpret_cast<const short8*>(Qp + ((size_t)h * TT + qrow) * 32 + 8 * g);
  f32x4 o0 = zz, o1 = zz;
  float mst = -1e30f, lsum = 0.f;
  int cur = 0;
  // prologue: stage tile 0 into buf 0
  __builtin_amdgcn_global_load_lds(
      (const __attribute__((address_space(1))) void*)Kh,
      (__attribute__((address_space(3))) void*)(lK[0] + tid * 8), 16, 0, 0);
  __builtin_amdgcn_global_load_lds(
      (const __attribute__((address_space(1))) void*)Vh,
      (__attribute__((address_space(3))) void*)(lV[0] + tid * 8), 16, 0, 0);

  for (int it = 0; it < nt; ++it) {
    __syncthreads();  // buf[cur] staged + all waves done with buf[cur^1]
    if (it + 1 < nt) {
      const int kv1 = (it + 1) * 64;
      __builtin_amdgcn_global_load_lds(
          (const __attribute__((address_space(1))) void*)(Kh + (size_t)kv1 * 32),
          (__attribute__((address_space(3))) void*)(lK[cur ^ 1] + tid * 8), 16, 0, 0);
      __builtin_amdgcn_global_load_lds(
          (const __attribute__((address_space(1))) void*)(Vh + kv1),
          (__attribute__((address_space(3))) void*)(lV[cur ^ 1] + tid * 8), 16, 0, 0);
    }
    // K fragments: addr = base + lane*16 (conflict-free)
    const char* kb = (const char*)lK[cur];
    short8 kf[4];
#pragma unroll
    for (int ct = 0; ct < 4; ++ct)
      kf[ct] = *reinterpret_cast<const short8*>(kb + ct * 1024 + lane * 16);
    // V fragments: addr = base + lane*16 (conflict-free)
    const char* vb = (const char*)lV[cur];
    const short8 v00 = *reinterpret_cast<const short8*>(vb + lane * 16);
    const short8 v10 = *reinterpret_cast<const short8*>(vb + 1024 + lane * 16);
    const short8 v01 = *reinterpret_cast<const short8*>(vb + 2048 + lane * 16);
    const short8 v11 = *reinterpret_cast<const short8*>(vb + 3072 + lane * 16);
    f32x4 s[4];
#pragma unroll
    for (int ct = 0; ct < 4; ++ct)
      s[ct] = __builtin_amdgcn_mfma_f32_16x16x32_bf16(kf[ct], qf, zz, 0, 0, 0);  // swapped
    if (it == nt - 1) {  // diagonal tile: mask k > q
#pragma unroll
      for (int ct = 0; ct < 4; ++ct)
#pragma unroll
        for (int j = 0; j < 4; ++j)
          if (ct * 16 + g * 4 + j > w * 16 + c) s[ct][j] = -1e30f;
    }
    // in-lane max over 16 scores
    float m01 = fmaxf(fmaxf(s[0][0], s[0][1]), fmaxf(s[0][2], s[0][3]));
    float m23 = fmaxf(fmaxf(s[1][0], s[1][1]), fmaxf(s[1][2], s[1][3]));
    float m45 = fmaxf(fmaxf(s[2][0], s[2][1]), fmaxf(s[2][2], s[2][3]));
    float m67 = fmaxf(fmaxf(s[3][0], s[3][1]), fmaxf(s[3][2], s[3][3]));
    float pm_ = fmaxf(fmaxf(m01, m23), fmaxf(m45, m67));
    if (__any(pm_ > mst + 8.0f)) {  // defer-max
      float pm2 = fmaxf(pm_, __shfl_xor(pm_, 16, 64));
      pm2 = fmaxf(pm2, __shfl_xor(pm2, 32, 64));
      const float nm = fmaxf(mst, pm2);
      const float alpha = exp2f(mst - nm);
      mst = nm;
      lsum *= alpha;
#pragma unroll
      for (int j = 0; j < 4; ++j) { o0[j] *= alpha; o1[j] *= alpha; }
    }
    float ts = 0.f;
#pragma unroll
    for (int ct = 0; ct < 4; ++ct) {
#pragma unroll
      for (int j = 0; j < 4; ++j) s[ct][j] = exp2f(s[ct][j] - mst);
      ts += (s[ct][0] + s[ct][1]) + (s[ct][2] + s[ct][3]);
    }
    lsum += ts;
    // P -> LDS (packed bf16 pairs), per-wave private slice (2-way max: free)
#pragma unroll
    for (int ct = 0; ct < 4; ++ct) {
      float2 p01; p01.x = s[ct][0]; p01.y = s[ct][1];
      float2 p23; p23.x = s[ct][2]; p23.y = s[ct][3];
      __hip_bfloat162 b01 = __float22bfloat162_rn(p01);
      __hip_bfloat162 b23 = __float22bfloat162_rn(p23);
      *reinterpret_cast<__hip_bfloat162*>(&Plds[w][c][ct * 16 + g * 4]) = b01;
      *reinterpret_cast<__hip_bfloat162*>(&Plds[w][c][ct * 16 + g * 4 + 2]) = b23;
    }
    const short8 pf0 = *reinterpret_cast<const short8*>(&Plds[w][c][8 * g]);
    const short8 pf1 = *reinterpret_cast<const short8*>(&Plds[w][c][32 + 8 * g]);
    // O^T: C col = q-row = lane c
    o0 = __builtin_amdgcn_mfma_f32_16x16x32_bf16(v00, pf0, o0, 0, 0, 0);
    o0 = __builtin_amdgcn_mfma_f32_16x16x32_bf16(v01, pf1, o0, 0, 0, 0);
    o1 = __builtin_amdgcn_mfma_f32_16x16x32_bf16(v10, pf0, o1, 0, 0, 0);
    o1 = __builtin_amdgcn_mfma_f32_16x16x32_bf16(v11, pf1, o1, 0, 0, 0);
    cur ^= 1;
  }
  // final lsum reduce across g-lanes of row c; write Ob
  lsum += __shfl_xor(lsum, 16, 64);
  lsum += __shfl_xor(lsum, 32, 64);
  const float inv = 1.0f / lsum;
  __hip_bfloat16* dst = Ob + (size_t)qrow * DATTN + h * 32;
  short4v w0, w1;
#pragma unroll
  for (int j = 0; j < 4; ++j) { w0[j] = f2bf(o0[j] * inv); w1[j] = f2bf(o1[j] * inv); }
  *reinterpret_cast<short4v*>(dst + g * 4) = w0;
  *reinterpret_cast<short4v*>(dst + 16 + g * 4) = w1;
}

extern "C" void kernel_launch(void* const* d_in, const int* in_sizes, int n_in,
                              void* d_out, int out_size, void* d_ws, size_t ws_size,
                              hipStream_t stream) {
  const float* x   = (const float*)d_in[0];
  const float* qsw = (const float*)d_in[1];
  const float* ksw = (const float*)d_in[2];
  const float* qgw = (const float*)d_in[3];
  const float* kgw = (const float*)d_in[4];
  const float* vw  = (const float*)d_in[5];
  const float* ow  = (const float*)d_in[6];
  const float* ls  = (const float*)d_in[7];
  const int* posp  = (const int*)d_in[9];

  size_t off = 0;
  auto alloc = [&](size_t bytes) {
    char* p = (char*)d_ws + off;
    off += (bytes + 255) & ~(size_t)255;
    return (void*)p;
  };
  __hip_bfloat16* Xbf  = (__hip_bfloat16*)alloc((size_t)TT * DM * 2);
  __hip_bfloat16* Wcat = (__hip_bfloat16*)alloc((size_t)NPROJ * DM * 2);
  __hip_bfloat16* OW   = (__hip_bfloat16*)alloc((size_t)DM * DATTN * 2);
  __hip_bfloat16* proj = (__hip_bfloat16*)alloc((size_t)TT * NPROJ * 2);
  __hip_bfloat16* Qp   = (__hip_bfloat16*)alloc((size_t)NH * TT * 32 * 2);
  __hip_bfloat16* Kpk  = (__hip_bfloat16*)alloc((size_t)NH * TT * 32 * 2);
  __hip_bfloat16* Vt   = (__hip_bfloat16*)alloc((size_t)NH * 32 * TT * 2);
  __hip_bfloat16* Ob   = (__hip_bfloat16*)alloc((size_t)TT * DATTN * 2);

  k_prep<<<dim3(NB_X + NB_OW + NB_WC), 256, 0, stream>>>(x, ow, qsw, ksw, qgw, kgw, vw,
                                                         Xbf, OW, Wcat);
  k_gemm_bt<1><<<dim3(TT / 64, NPROJ / 128), 256, 0, stream>>>(Xbf, Wcat, (void*)proj,
                                                               TT, NPROJ, DM);
  k_rope_pack<<<dim3(TT * NH / 256), 256, 0, stream>>>(proj, ls, posp, Qp, Kpk, Vt);
  k_attn<<<dim3(1024), 256, 0, stream>>>(Qp, Kpk, Vt, Ob);
  k_gemm_bt<0><<<dim3(TT / 64, DM / 128), 256, 0, stream>>>(Ob, OW, (void*)d_out,
                                                            TT, DM, DATTN);
}